// Round 5
// baseline (2702.613 us; speedup 1.0000x reference)
//
#include <hip/hip_runtime.h>

typedef short bf16x8 __attribute__((ext_vector_type(8)));
typedef float f32x4 __attribute__((ext_vector_type(4)));
typedef float f32x2 __attribute__((ext_vector_type(2)));
typedef unsigned short u16;
typedef unsigned int u32;
typedef unsigned long long u64;

#define NPTS 16384
#define NPOINT 1024
#define STOT 524288   // 16*1024*32 samples

__device__ __forceinline__ u16 f2bf(float f){
  u32 u = __builtin_bit_cast(u32, f);
  u += 0x7fffu + ((u >> 16) & 1u);
  return (u16)(u >> 16);
}
__device__ __forceinline__ float bf2f(u16 u){
  u32 x = ((u32)u) << 16;
  return __builtin_bit_cast(float, x);
}

// 64-bit max-combine across lanes via DPP (pure VALU, no DS pipe).
template<int CTRL>
__device__ __forceinline__ u64 dpp_max(u64 key){
  u32 lo = (u32)key, hi = (u32)(key >> 32);
  u32 lo1 = (u32)__builtin_amdgcn_update_dpp(0, (int)lo, CTRL, 0xf, 0xf, true);
  u32 hi1 = (u32)__builtin_amdgcn_update_dpp(0, (int)hi, CTRL, 0xf, 0xf, true);
  u64 k1 = ((u64)hi1 << 32) | (u64)lo1;
  return (k1 > key) ? k1 : key;
}
__device__ __forceinline__ u64 umax64(u64 a, u64 b){ return (a > b) ? a : b; }
__device__ __forceinline__ u64 packkey(float d, int idx){
  // d >= 0 so uint order on float bits == float order; ~idx -> ties pick smaller orig idx
  return ((u64)__builtin_bit_cast(u32, d) << 32) | (u64)(u32)(~(u32)idx);
}
__device__ __forceinline__ u32 spread3(int v){   // 4 bits -> positions 0,3,6,9
  u32 x = (u32)v;
  return (x & 1u) | ((x & 2u) << 2) | ((x & 4u) << 4) | ((x & 8u) << 6);
}
__device__ __forceinline__ float wred_sum(float v){
#pragma unroll
  for (int off = 1; off < 64; off <<= 1) v += __shfl_xor(v, off, 64);
  return v;
}
__device__ __forceinline__ float wred_max(float v){
#pragma unroll
  for (int off = 1; off < 64; off <<= 1) v = fmaxf(v, __shfl_xor(v, off, 64));
  return v;
}

// ---------------------------------------------------------------- FPS (bucket-pruned, exact)
// One block per batch. One-time: Morton-cell binning of the 16384 points into a
// sorted array (equal buckets of 256 contiguous sorted points; wave w owns
// buckets 4w..4w+3, 4 pts/lane/bucket, coords+dist in registers).
// Per iter: bucket skipped iff (0.999*d(c,ctr)-r)^2 >= bmax*1.0001 (triangle
// inequality + margins dwarfing fp error => skipped buckets bit-exactly
// unchanged). Unpruned: update 4 pts/lane, rebuild bucket (max,~idx) key via
// DPP chain. Global argmax: 64 bucket keys snapshotted into ping-pong LDS each
// iter (safe: slot parity p rewritten only after barrier i+1, by which every
// wave has finished reading parity p of iter i), ONE barrier, 4 ds_read_b64 +
// 4 DPP levels. Ties exact via ~origidx in every key.
__global__ __launch_bounds__(1024) void fps_kernel(const float* __restrict__ xyz,
                                                   const int* __restrict__ finit,
                                                   float4* __restrict__ xpk_all,
                                                   float4* __restrict__ xps_all,
                                                   float* __restrict__ out0){
  __shared__ u32 hist[4096];
  __shared__ u32 wsum[16];
  __shared__ u64 par[2][64];
  const int b = blockIdx.x, t = threadIdx.x;
  const int wave = t >> 6, lane = t & 63;
  const float* xb = xyz + (size_t)b * 3 * NPTS;
  float4* xpk = xpk_all + (size_t)b * NPTS;   // coords by ORIGINAL index (center fetch)
  float4* xps = xps_all + (size_t)b * NPTS;   // coords+idx in sorted (Morton-cell) order

  // ---- phase A: load, publish xpk, cell id + rank
  for (int i = t; i < 4096; i += 1024) hist[i] = 0;
  __syncthreads();
  u32 cr[16];
#pragma unroll
  for (int k = 0; k < 16; k++){
    int n = (k << 10) + t;
    float x = xb[n], y = xb[NPTS + n], z = xb[2*NPTS + n];
    xpk[n] = make_float4(x, y, z, 0.f);
    int xi = (int)fminf(fmaxf((x + 4.5f)*1.7777778f, 0.f), 15.f);
    int yi = (int)fminf(fmaxf((y + 4.5f)*1.7777778f, 0.f), 15.f);
    int zi = (int)fminf(fmaxf((z + 4.5f)*1.7777778f, 0.f), 15.f);
    u32 cell = spread3(xi) | (spread3(yi) << 1) | (spread3(zi) << 2);
    u32 rank = atomicAdd(&hist[cell], 1u);
    cr[k] = (cell << 16) | rank;
  }
  __syncthreads();
  // ---- phase B: exclusive prefix sum over 4096 cell counts
  uint4 hv = *(const uint4*)&hist[4*t];
  u32 s = hv.x + hv.y + hv.z + hv.w;
  u32 sInc = s;
#pragma unroll
  for (int off = 1; off < 64; off <<= 1){
    u32 nv = (u32)__shfl_up((int)sInc, off, 64);
    if (lane >= off) sInc += nv;
  }
  if (lane == 63) wsum[wave] = sInc;
  __syncthreads();
  u32 wb = 0;
#pragma unroll
  for (int i = 0; i < 16; i++) if (i < wave) wb += wsum[i];
  u32 ex = wb + sInc - s;
  hist[4*t]   = ex;
  hist[4*t+1] = ex + hv.x;
  hist[4*t+2] = ex + hv.x + hv.y;
  hist[4*t+3] = ex + hv.x + hv.y + hv.z;
  __syncthreads();
  // ---- phase C: scatter to sorted order (pos unique by construction)
#pragma unroll
  for (int k = 0; k < 16; k++){
    int n = (k << 10) + t;
    float4 pnt = xpk[n];
    u32 cell = cr[k] >> 16, rank = cr[k] & 0xFFFFu;
    u32 pos = hist[cell] + rank;
    pnt.w = __int_as_float(n);
    xps[pos] = pnt;
  }
  __syncthreads();   // per-wave vmcnt drained before barrier; first-ever read of xps after this
  // ---- phase D: register-load this lane's 16 sorted points (4 per bucket)
  f32x2 px[8], py[8], pz[8], dist[8];
  int idxv[16];
#pragma unroll
  for (int q = 0; q < 4; q++){
#pragma unroll
    for (int jj = 0; jj < 4; jj++){
      int pos = (wave << 10) + (q << 8) + (jj << 6) + lane;
      float4 sp = xps[pos];
      int pr = 2*q + (jj >> 1), hf = jj & 1;
      px[pr][hf] = sp.x; py[pr][hf] = sp.y; pz[pr][hf] = sp.z;
      dist[pr][hf] = 1e10f;
      idxv[4*q + jj] = __float_as_int(sp.w);
    }
  }
  // ---- phase E: bucket metadata (centroid, margin radius)
  float ctrx[4], ctry[4], ctrz[4], rad[4], bmax[4];
  u64 kb[4];
#pragma unroll
  for (int q = 0; q < 4; q++){
    f32x2 sx2 = px[2*q] + px[2*q+1];
    f32x2 sy2 = py[2*q] + py[2*q+1];
    f32x2 sz2 = pz[2*q] + pz[2*q+1];
    float cx = wred_sum(sx2.x + sx2.y) * (1.f/256.f);
    float cy = wred_sum(sy2.x + sy2.y) * (1.f/256.f);
    float cz = wred_sum(sz2.x + sz2.y) * (1.f/256.f);
    float m2 = 0.f;
#pragma unroll
    for (int pr = 0; pr < 2; pr++){
#pragma unroll
      for (int hf = 0; hf < 2; hf++){
        float dx = px[2*q+pr][hf] - cx, dy = py[2*q+pr][hf] - cy, dz = pz[2*q+pr][hf] - cz;
        m2 = fmaxf(m2, dx*dx + dy*dy + dz*dz);
      }
    }
    m2 = wred_max(m2);
    ctrx[q] = __builtin_bit_cast(float, __builtin_amdgcn_readfirstlane(__builtin_bit_cast(int, cx)));
    ctry[q] = __builtin_bit_cast(float, __builtin_amdgcn_readfirstlane(__builtin_bit_cast(int, cy)));
    ctrz[q] = __builtin_bit_cast(float, __builtin_amdgcn_readfirstlane(__builtin_bit_cast(int, cz)));
    rad[q]  = sqrtf(m2) * 1.0001f + 1e-6f;
    bmax[q] = 1e10f;   // no pruning until first rebuild
    kb[q]   = 0ULL;
  }
  // ---- main loop
  int nbu = finit[b];
  int p = 0;
  for (int it = 0; it < NPOINT; it++){
    float4 cc = xpk[nbu];   // uniform index; L2-resident (256 KB/batch)
    if (t == 0){
      out0[((size_t)b*3 + 0)*NPOINT + it] = cc.x;
      out0[((size_t)b*3 + 1)*NPOINT + it] = cc.y;
      out0[((size_t)b*3 + 2)*NPOINT + it] = cc.z;
    }
#pragma unroll
    for (int q = 0; q < 4; q++){
      float exx = cc.x - ctrx[q], eyy = cc.y - ctry[q], ezz = cc.z - ctrz[q];
      float sd = sqrtf(exx*exx + eyy*eyy + ezz*ezz);
      float tt = sd * 0.999f - rad[q];
      bool doit = !((tt > 0.f) && (tt*tt >= bmax[q]));
      if (__builtin_amdgcn_readfirstlane((int)doit)){
        {
#pragma clang fp contract(off)
          f32x2 cx2 = {cc.x, cc.x}, cy2 = {cc.y, cc.y}, cz2 = {cc.z, cc.z};
#pragma unroll
          for (int pr = 0; pr < 2; pr++){
            int ii = 2*q + pr;
            f32x2 dx = px[ii] - cx2;
            f32x2 dy = py[ii] - cy2;
            f32x2 dz = pz[ii] - cz2;
            f32x2 dd = dx*dx + dy*dy + dz*dz;   // matches reference eval order
            dist[ii] = __builtin_elementwise_min(dist[ii], dd);
          }
        }
        u64 k0 = packkey(dist[2*q].x,   idxv[4*q+0]);
        u64 k1 = packkey(dist[2*q].y,   idxv[4*q+1]);
        u64 k2 = packkey(dist[2*q+1].x, idxv[4*q+2]);
        u64 k3 = packkey(dist[2*q+1].y, idxv[4*q+3]);
        u64 km = umax64(umax64(k0, k1), umax64(k2, k3));
        km = dpp_max<0xB1>(km);   // xor1
        km = dpp_max<0x4E>(km);   // xor2
        km = dpp_max<0x141>(km);  // half_mirror (xor4 on quad-uniform)
        km = dpp_max<0x140>(km);  // mirror (xor8)
        km = dpp_max<0x142>(km);  // bcast15
        km = dpp_max<0x143>(km);  // bcast31 -> lane63 has bucket max
        u32 klo = (u32)__builtin_amdgcn_readlane((int)(u32)km, 63);
        u32 khi = (u32)__builtin_amdgcn_readlane((int)(u32)(km >> 32), 63);
        bmax[q] = __builtin_bit_cast(float, khi) * 1.0001f;  // pre-margined for the prune test
        kb[q] = ((u64)khi << 32) | (u64)klo;                 // wave-uniform bucket key
      }
    }
    // snapshot the 4 (uniform) bucket keys via lane-select (no writelane on gfx950)
    u64 kv = (lane == 0) ? kb[0] : (lane == 1) ? kb[1] : (lane == 2) ? kb[2] : kb[3];
    if (lane < 4) par[p][4*wave + lane] = kv;
    __syncthreads();
    int sl = lane & 15;
    u64 m0 = par[p][sl], m1 = par[p][sl+16], m2 = par[p][sl+32], m3 = par[p][sl+48];
    u64 mm = umax64(umax64(m0, m1), umax64(m2, m3));
    mm = dpp_max<0xB1>(mm);
    mm = dpp_max<0x4E>(mm);
    mm = dpp_max<0x141>(mm);
    mm = dpp_max<0x140>(mm);   // uniform within each 16-group; groups identical
    nbu = __builtin_amdgcn_readfirstlane((int)~(u32)mm);
    p ^= 1;
  }
}

// ---------------------------------------------------------------- pack XP[b][n][96] bf16 (xyz || points, zero pad)
__global__ __launch_bounds__(256) void pack_kernel(const float* __restrict__ xyz,
                                                   const float* __restrict__ points,
                                                   u16* __restrict__ XP){
  __shared__ float ldsb[67*256];
  const int blk = blockIdx.x, t = threadIdx.x;
  const int b = blk >> 6;
  const int n0 = (blk & 63) << 8;
  for (int c = 0; c < 67; c++){
    const float* src = (c < 3) ? (xyz + ((size_t)b*3 + c)*NPTS)
                               : (points + ((size_t)b*64 + (c-3))*NPTS);
    ldsb[c*256 + t] = src[n0 + t];
  }
  __syncthreads();
  u16* dst = XP + ((size_t)b*NPTS + n0)*96;
  for (int itc = 0; itc < 12; itc++){
    int q = t + (itc << 8);          // 3072 16B-chunks, consecutive => coalesced
    int r = q / 12, ch = q % 12;
    u16 tmp[8];
#pragma unroll
    for (int j = 0; j < 8; j++){
      int c = ch*8 + j;
      tmp[j] = (c < 67) ? f2bf(ldsb[c*256 + r]) : (u16)0;
    }
    uint4 v;
    v.x = (u32)tmp[0] | ((u32)tmp[1] << 16);
    v.y = (u32)tmp[2] | ((u32)tmp[3] << 16);
    v.z = (u32)tmp[4] | ((u32)tmp[5] << 16);
    v.w = (u32)tmp[6] | ((u32)tmp[7] << 16);
    *(uint4*)(dst + q*8) = v;
  }
}

// ---------------------------------------------------------------- small prep: zero stat buckets + pack weights bf16
__global__ __launch_bounds__(256) void prep_small(const float* __restrict__ W0,
                                                  const float* __restrict__ W1,
                                                  const float* __restrict__ W2,
                                                  u16* __restrict__ W0bf,
                                                  u16* __restrict__ W1bf,
                                                  u16* __restrict__ W2bf,
                                                  float* __restrict__ statsF){
  const int blk = blockIdx.x, t = threadIdx.x;
  if (blk < 48){
#pragma unroll
    for (int k = 0; k < 4; k++) statsF[blk*1024 + k*256 + t] = 0.f;
  } else if (blk == 48){
    for (int i = t; i < 64*96; i += 256){
      int n = i / 96, k = i % 96;
      W0bf[i] = (k < 67) ? f2bf(W0[n*67 + k]) : (u16)0;
    }
  } else if (blk <= 50){
    for (int i = (blk-49)*256 + t; i < 128*64; i += 512) W1bf[i] = f2bf(W1[i]);
  } else if (blk <= 54){
    for (int i = (blk-51)*256 + t; i < 128*128; i += 1024) W2bf[i] = f2bf(W2[i]);
  }
}

// ---------------------------------------------------------------- layer 0: gather + matmul (K=96 padded), stats
__global__ __launch_bounds__(256) void l0_kernel(const u16* __restrict__ XP,
                                                 const int* __restrict__ gidx,
                                                 const u16* __restrict__ W0bf,
                                                 u16* __restrict__ y0,
                                                 float* __restrict__ bsum, float* __restrict__ bsqr){
  __shared__ float lsum[64], lsqr[64];
  const int blk = blockIdx.x, t = threadIdx.x;
  const int b = blk >> 8, j = blk & 255;
  const int wave = t >> 6, lane = t & 63, lrow = lane & 15, lq = lane >> 4;
  if (t < 64){ lsum[t] = 0.f; lsqr[t] = 0.f; }
  __syncthreads();
  const size_t srow = (size_t)blk * 128;
  const int m0 = wave*32 + lrow, m1 = m0 + 16;
  const int gbase = b*32768 + j*128;
  const int p0 = gidx[gbase + m0];
  const int p1 = gidx[gbase + m1];
  const bf16x8* ar0 = (const bf16x8*)(XP + ((size_t)b*NPTS + p0)*96);
  const bf16x8* ar1 = (const bf16x8*)(XP + ((size_t)b*NPTS + p1)*96);
  f32x4 acc[2][4];
#pragma unroll
  for (int mt = 0; mt < 2; mt++)
#pragma unroll
    for (int nt = 0; nt < 4; nt++){ f32x4 z = {0.f,0.f,0.f,0.f}; acc[mt][nt] = z; }
#pragma unroll
  for (int ks = 0; ks < 3; ks++){
    bf16x8 af0 = ar0[ks*4 + lq];
    bf16x8 af1 = ar1[ks*4 + lq];
#pragma unroll
    for (int nt = 0; nt < 4; nt++){
      bf16x8 bb = *(const bf16x8*)(W0bf + (nt*16 + lrow)*96 + ks*32 + lq*8);
      acc[0][nt] = __builtin_amdgcn_mfma_f32_16x16x32_bf16(af0, bb, acc[0][nt], 0, 0, 0);
      acc[1][nt] = __builtin_amdgcn_mfma_f32_16x16x32_bf16(af1, bb, acc[1][nt], 0, 0, 0);
    }
  }
#pragma unroll
  for (int nt = 0; nt < 4; nt++){
    float s = 0.f, s2 = 0.f;
#pragma unroll
    for (int mt = 0; mt < 2; mt++){
#pragma unroll
      for (int i = 0; i < 4; i++){
        float u = acc[mt][nt][i];
        s += u; s2 = fmaf(u, u, s2);
        int m = wave*32 + mt*16 + lq*4 + i;
        y0[(srow + m)*64 + nt*16 + lrow] = f2bf(u);
      }
    }
    s  += __shfl_xor(s, 16, 64);  s  += __shfl_xor(s, 32, 64);
    s2 += __shfl_xor(s2, 16, 64); s2 += __shfl_xor(s2, 32, 64);
    if (lane < 16){ atomicAdd(&lsum[nt*16 + lane], s); atomicAdd(&lsqr[nt*16 + lane], s2); }
  }
  __syncthreads();
  if (t < 64){
    int bkt = blk & 63;
    atomicAdd(&bsum[bkt*128 + t], lsum[t]);
    atomicAdd(&bsqr[bkt*128 + t], lsqr[t]);
  }
}

// ---------------------------------------------------------------- stats finalize: a = g*rsqrt(var+eps), d = be - mean*a
__global__ __launch_bounds__(128) void stats_kernel(const float* __restrict__ bsum,
                                                    const float* __restrict__ bsqr,
                                                    const float* __restrict__ g,
                                                    const float* __restrict__ be,
                                                    float* __restrict__ a, float* __restrict__ d, int C){
  const int c = threadIdx.x;
  if (c >= C) return;
  float s = 0.f, s2 = 0.f;
  for (int k = 0; k < 64; k++){ s += bsum[k*128 + c]; s2 += bsqr[k*128 + c]; }
  const float inv = 1.f / (float)STOT;
  float m = s * inv;
  float v = s2 * inv - m*m;
  float aa = g[c] / sqrtf(v + 1e-5f);
  a[c] = aa;
  d[c] = be[c] - m*aa;
}

__device__ __forceinline__ bf16x8 load_bn_relu(const u16* __restrict__ row, int ko,
                                               const float* __restrict__ av,
                                               const float* __restrict__ dv){
  uint4 r = *(const uint4*)(row + ko);
  u32 w[4] = {r.x, r.y, r.z, r.w};
  bf16x8 out;
#pragma unroll
  for (int jj = 0; jj < 8; jj++){
    u16 us = (u16)(w[jj >> 1] >> ((jj & 1) * 16));
    float h = fmaxf(fmaf(av[ko + jj], bf2f(us), dv[ko + jj]), 0.f);
    out[jj] = (short)f2bf(h);
  }
  return out;
}

// ---------------------------------------------------------------- layer 1: K=64 -> Cout=128
__global__ __launch_bounds__(256) void l1_kernel(const u16* __restrict__ y0,
                                                 const u16* __restrict__ W1bf,
                                                 const float* __restrict__ a0, const float* __restrict__ d0,
                                                 u16* __restrict__ y1,
                                                 float* __restrict__ bsum, float* __restrict__ bsqr){
  __shared__ float lsum[128], lsqr[128];
  __shared__ float av[64], dv[64];
  const int blk = blockIdx.x, t = threadIdx.x;
  const int wave = t >> 6, lane = t & 63, lrow = lane & 15, lq = lane >> 4;
  if (t < 128){ lsum[t] = 0.f; lsqr[t] = 0.f; }
  if (t < 64){ av[t] = a0[t]; dv[t] = d0[t]; }
  __syncthreads();
  const size_t srow = (size_t)blk * 128;
  const int m0 = wave*32 + lrow, m1 = m0 + 16;
  const u16* row0 = y0 + (srow + m0)*64;
  const u16* row1 = y0 + (srow + m1)*64;
  f32x4 acc[2][8];
#pragma unroll
  for (int mt = 0; mt < 2; mt++)
#pragma unroll
    for (int nt = 0; nt < 8; nt++){ f32x4 z = {0.f,0.f,0.f,0.f}; acc[mt][nt] = z; }
#pragma unroll
  for (int ks = 0; ks < 2; ks++){
    const int ko = ks*32 + lq*8;
    bf16x8 af0 = load_bn_relu(row0, ko, av, dv);
    bf16x8 af1 = load_bn_relu(row1, ko, av, dv);
#pragma unroll
    for (int nt = 0; nt < 8; nt++){
      bf16x8 bb = *(const bf16x8*)(W1bf + (nt*16 + lrow)*64 + ko);
      acc[0][nt] = __builtin_amdgcn_mfma_f32_16x16x32_bf16(af0, bb, acc[0][nt], 0, 0, 0);
      acc[1][nt] = __builtin_amdgcn_mfma_f32_16x16x32_bf16(af1, bb, acc[1][nt], 0, 0, 0);
    }
  }
#pragma unroll
  for (int nt = 0; nt < 8; nt++){
    float s = 0.f, s2 = 0.f;
#pragma unroll
    for (int mt = 0; mt < 2; mt++){
#pragma unroll
      for (int i = 0; i < 4; i++){
        float u = acc[mt][nt][i];
        s += u; s2 = fmaf(u, u, s2);
        int m = wave*32 + mt*16 + lq*4 + i;
        y1[(srow + m)*128 + nt*16 + lrow] = f2bf(u);
      }
    }
    s  += __shfl_xor(s, 16, 64);  s  += __shfl_xor(s, 32, 64);
    s2 += __shfl_xor(s2, 16, 64); s2 += __shfl_xor(s2, 32, 64);
    if (lane < 16){ atomicAdd(&lsum[nt*16 + lane], s); atomicAdd(&lsqr[nt*16 + lane], s2); }
  }
  __syncthreads();
  if (t < 128){
    int bkt = blk & 63;
    atomicAdd(&bsum[bkt*128 + t], lsum[t]);
    atomicAdd(&bsqr[bkt*128 + t], lsqr[t]);
  }
}

// ---------------------------------------------------------------- layer 2: K=128 -> Cout=128; emit per-group max/min of pre-BN y2
__global__ __launch_bounds__(256) void l2_kernel(const u16* __restrict__ y1,
                                                 const u16* __restrict__ W2bf,
                                                 const float* __restrict__ a1, const float* __restrict__ d1,
                                                 float* __restrict__ maxb, float* __restrict__ minb,
                                                 float* __restrict__ bsum, float* __restrict__ bsqr){
  __shared__ float lsum[128], lsqr[128];
  __shared__ float av[128], dv[128];
  const int blk = blockIdx.x, t = threadIdx.x;
  const int wave = t >> 6, lane = t & 63, lrow = lane & 15, lq = lane >> 4;
  if (t < 128){ lsum[t] = 0.f; lsqr[t] = 0.f; av[t] = a1[t]; dv[t] = d1[t]; }
  __syncthreads();
  const size_t srow = (size_t)blk * 128;
  const int m0 = wave*32 + lrow, m1 = m0 + 16;
  const u16* row0 = y1 + (srow + m0)*128;
  const u16* row1 = y1 + (srow + m1)*128;
  f32x4 acc[2][8];
#pragma unroll
  for (int mt = 0; mt < 2; mt++)
#pragma unroll
    for (int nt = 0; nt < 8; nt++){ f32x4 z = {0.f,0.f,0.f,0.f}; acc[mt][nt] = z; }
#pragma unroll
  for (int ks = 0; ks < 4; ks++){
    const int ko = ks*32 + lq*8;
    bf16x8 af0 = load_bn_relu(row0, ko, av, dv);
    bf16x8 af1 = load_bn_relu(row1, ko, av, dv);
#pragma unroll
    for (int nt = 0; nt < 8; nt++){
      bf16x8 bb = *(const bf16x8*)(W2bf + (nt*16 + lrow)*128 + ko);
      acc[0][nt] = __builtin_amdgcn_mfma_f32_16x16x32_bf16(af0, bb, acc[0][nt], 0, 0, 0);
      acc[1][nt] = __builtin_amdgcn_mfma_f32_16x16x32_bf16(af1, bb, acc[1][nt], 0, 0, 0);
    }
  }
#pragma unroll
  for (int nt = 0; nt < 8; nt++){
    float s = 0.f, s2 = 0.f, mx = -3.4e38f, mn = 3.4e38f;
#pragma unroll
    for (int mt = 0; mt < 2; mt++){
#pragma unroll
      for (int i = 0; i < 4; i++){
        float u = acc[mt][nt][i];
        s += u; s2 = fmaf(u, u, s2);
        mx = fmaxf(mx, u); mn = fminf(mn, u);
      }
    }
    s  += __shfl_xor(s, 16, 64);  s  += __shfl_xor(s, 32, 64);
    s2 += __shfl_xor(s2, 16, 64); s2 += __shfl_xor(s2, 32, 64);
    mx = fmaxf(mx, __shfl_xor(mx, 16, 64)); mx = fmaxf(mx, __shfl_xor(mx, 32, 64));
    mn = fminf(mn, __shfl_xor(mn, 16, 64)); mn = fminf(mn, __shfl_xor(mn, 32, 64));
    if (lane < 16){
      size_t gi = ((size_t)blk*4 + wave)*128 + nt*16 + lane;
      maxb[gi] = mx; minb[gi] = mn;
      atomicAdd(&lsum[nt*16 + lane], s); atomicAdd(&lsqr[nt*16 + lane], s2);
    }
  }
  __syncthreads();
  if (t < 128){
    int bkt = blk & 63;
    atomicAdd(&bsum[bkt*128 + t], lsum[t]);
    atomicAdd(&bsqr[bkt*128 + t], lsqr[t]);
  }
}

// ---------------------------------------------------------------- final: BN2+relu on group max/min, transpose-store [B,128,NP]
__global__ __launch_bounds__(256) void final_kernel(const float* __restrict__ maxb,
                                                    const float* __restrict__ minb,
                                                    const float* __restrict__ a2, const float* __restrict__ d2,
                                                    float* __restrict__ out1){
  __shared__ float ldsb[64*129];
  __shared__ float av[128], dv[128];
  const int blk = blockIdx.x, t = threadIdx.x;
  const int b = blk >> 4, np0 = (blk & 15) << 6;
  if (t < 128){ av[t] = a2[t]; dv[t] = d2[t]; }
  __syncthreads();
  const size_t base = ((size_t)b*NPOINT + np0)*128;
  for (int itc = 0; itc < 32; itc++){
    int e = t + (itc << 8);
    int npl = e >> 7, c = e & 127;
    float a = av[c];
    float mxv = maxb[base + e], mnv = minb[base + e];
    float vsel = (a >= 0.f) ? mxv : mnv;
    ldsb[npl*129 + c] = fmaxf(fmaf(a, vsel, dv[c]), 0.f);
  }
  __syncthreads();
  for (int itc = 0; itc < 32; itc++){
    int e = t + (itc << 8);
    int c = e >> 6, npl = e & 63;
    out1[((size_t)b*128 + c)*NPOINT + np0 + npl] = ldsb[npl*129 + c];
  }
}

// ---------------------------------------------------------------- launch
extern "C" void kernel_launch(void* const* d_in, const int* in_sizes, int n_in,
                              void* d_out, int out_size, void* d_ws, size_t ws_size,
                              hipStream_t stream) {
  const float* xyz    = (const float*)d_in[0];
  const float* points = (const float*)d_in[1];
  const int*   finit  = (const int*)d_in[2];
  const int*   gidx   = (const int*)d_in[3];
  const float* W0  = (const float*)d_in[4];
  const float* g0v = (const float*)d_in[6];
  const float* be0 = (const float*)d_in[7];
  const float* W1  = (const float*)d_in[8];
  const float* g1v = (const float*)d_in[10];
  const float* be1 = (const float*)d_in[11];
  const float* W2  = (const float*)d_in[12];
  const float* g2v = (const float*)d_in[14];
  const float* be2 = (const float*)d_in[15];

  float* out0 = (float*)d_out;
  float* out1 = out0 + 16*3*NPOINT;   // 49152

  char* ws = (char*)d_ws;
  u16* XP = (u16*)ws;                               // 48 MiB, dead after l0
  u16* y1 = (u16*)ws;                               // 128 MiB (aliases XP; written in l1)
  u16* y0 = (u16*)(ws + 134217728);                 // 64 MiB
  float4* xpk = (float4*)(ws + 134217728);          // 4 MiB, fps-only (fps completes before l0 writes y0)
  float4* xps = (float4*)(ws + 138412032);          // 4 MiB, fps-only (sorted copy)
  float* maxb = (float*)(ws + 134217728);           // aliases y0/xpk (dead after l1/fps)
  float* minb = (float*)(ws + 134217728 + 8388608);
  float* statsF = (float*)(ws + 201326592);
  float* bsum0 = statsF;          float* bsqr0 = statsF + 8192;
  float* bsum1 = statsF + 16384;  float* bsqr1 = statsF + 24576;
  float* bsum2 = statsF + 32768;  float* bsqr2 = statsF + 40960;
  float* a0 = statsF + 49152;       float* d0 = a0 + 128;
  float* a1 = statsF + 49152 + 256; float* d1 = a1 + 128;
  float* a2 = statsF + 49152 + 512; float* d2 = a2 + 128;
  u16* W0bf = (u16*)(statsF + 49920);
  u16* W1bf = W0bf + 64*96;
  u16* W2bf = W1bf + 128*64;

  fps_kernel<<<16, 1024, 0, stream>>>(xyz, finit, xpk, xps, out0);
  prep_small<<<64, 256, 0, stream>>>(W0, W1, W2, W0bf, W1bf, W2bf, statsF);
  pack_kernel<<<1024, 256, 0, stream>>>(xyz, points, XP);
  l0_kernel<<<4096, 256, 0, stream>>>(XP, gidx, W0bf, y0, bsum0, bsqr0);
  stats_kernel<<<1, 128, 0, stream>>>(bsum0, bsqr0, g0v, be0, a0, d0, 64);
  l1_kernel<<<4096, 256, 0, stream>>>(y0, W1bf, a0, d0, y1, bsum1, bsqr1);
  stats_kernel<<<1, 128, 0, stream>>>(bsum1, bsqr1, g1v, be1, a1, d1, 128);
  l2_kernel<<<4096, 256, 0, stream>>>(y1, W2bf, a1, d1, maxb, minb, bsum2, bsqr2);
  stats_kernel<<<1, 128, 0, stream>>>(bsum2, bsqr2, g2v, be2, a2, d2, 128);
  final_kernel<<<256, 256, 0, stream>>>(maxb, minb, a2, d2, out1);
}

// Round 6
// 2503.250 us; speedup vs baseline: 1.0796x; 1.0796x over previous
//
#include <hip/hip_runtime.h>

typedef short bf16x8 __attribute__((ext_vector_type(8)));
typedef float f32x4 __attribute__((ext_vector_type(4)));
typedef float f32x2 __attribute__((ext_vector_type(2)));
typedef unsigned short u16;
typedef unsigned int u32;
typedef unsigned long long u64;

#define NPTS 16384
#define NPOINT 1024
#define STOT 524288   // 16*1024*32 samples
#define NCB 240       // conv blocks (blocks 16..255)
#define NW  960       // conv workers (4-wave groups)

__device__ __forceinline__ u16 f2bf(float f){
  u32 u = __builtin_bit_cast(u32, f);
  u += 0x7fffu + ((u >> 16) & 1u);
  return (u16)(u >> 16);
}
__device__ __forceinline__ float bf2f(u16 u){
  u32 x = ((u32)u) << 16;
  return __builtin_bit_cast(float, x);
}

// 64-bit max-combine across lanes via DPP (pure VALU, no DS pipe).
template<int CTRL>
__device__ __forceinline__ u64 dpp_max(u64 key){
  u32 lo = (u32)key, hi = (u32)(key >> 32);
  u32 lo1 = (u32)__builtin_amdgcn_update_dpp(0, (int)lo, CTRL, 0xf, 0xf, true);
  u32 hi1 = (u32)__builtin_amdgcn_update_dpp(0, (int)hi, CTRL, 0xf, 0xf, true);
  u64 k1 = ((u64)hi1 << 32) | (u64)lo1;
  return (k1 > key) ? k1 : key;
}
__device__ __forceinline__ u64 umax64(u64 a, u64 b){ return (a > b) ? a : b; }

__device__ __forceinline__ void arrive(u32* c){
  __hip_atomic_fetch_add(c, 1u, __ATOMIC_RELEASE, __HIP_MEMORY_SCOPE_AGENT);
}
__device__ __forceinline__ void waitc(u32* c, u32 tgt){
  while (__hip_atomic_load(c, __ATOMIC_ACQUIRE, __HIP_MEMORY_SCOPE_AGENT) < tgt)
    __builtin_amdgcn_s_sleep(16);
}

struct FpsS  { u64 warr[2][16]; };
struct ConvS { float lsum[128]; float lsqr[128]; float av[128]; float dv[128]; };
union SMemU  { FpsS fps; ConvS conv; };

__device__ __forceinline__ bf16x8 load_bn_relu(const u16* __restrict__ row, int ko,
                                               const float* __restrict__ av,
                                               const float* __restrict__ dv){
  uint4 r = *(const uint4*)(row + ko);
  u32 w[4] = {r.x, r.y, r.z, r.w};
  bf16x8 out;
#pragma unroll
  for (int jj = 0; jj < 8; jj++){
    u16 us = (u16)(w[jj >> 1] >> ((jj & 1) * 16));
    float h = fmaxf(fmaf(av[ko + jj], bf2f(us), dv[ko + jj]), 0.f);
    out[jj] = (short)f2bf(h);
  }
  return out;
}

// zero the sync counters (ws is re-poisoned 0xAA before every call)
__global__ void zero_kernel(u32* __restrict__ ctrs){
  if (threadIdx.x < 64) ctrs[threadIdx.x] = 0;
}

// ================================================================ MEGA KERNEL
// blocks 0..15  : FPS (round-3 proven: 16 pts/thread, all-DPP u64 argmax,
//                 1 barrier/iter, ping-pong LDS, uniform-index center fetch)
// blocks 16..255: persistent conv chain, phases sequenced by device-scope
//                 arrive/spin counters. All 256 blocks co-resident
//                 (launch_bounds(1024) => VGPR<=128 => 1 block/CU).
__global__ __launch_bounds__(1024) void mega_kernel(
    const float* __restrict__ xyz, const float* __restrict__ points,
    const int* __restrict__ finit, const int* __restrict__ gidx,
    const float* __restrict__ W0, const float* __restrict__ g0v, const float* __restrict__ be0,
    const float* __restrict__ W1, const float* __restrict__ g1v, const float* __restrict__ be1,
    const float* __restrict__ W2, const float* __restrict__ g2v, const float* __restrict__ be2,
    float* __restrict__ out0, float* __restrict__ out1,
    u16* __restrict__ XP, u16* __restrict__ y0, u16* __restrict__ y1,
    float* __restrict__ maxb, float* __restrict__ minb,
    float* __restrict__ statsF, float4* __restrict__ xpk_all,
    u16* __restrict__ W0bf, u16* __restrict__ W1bf, u16* __restrict__ W2bf,
    u32* __restrict__ ctrs){
  __shared__ SMemU sm;
  const int t = threadIdx.x;
  const int wave = t >> 6, lane = t & 63;

  if (blockIdx.x < 16){
    // ------------------------------------------------------------ FPS path
    const int b = blockIdx.x;
    const float* xb = xyz + (size_t)b * 3 * NPTS;
    float4* xpk = xpk_all + (size_t)b * NPTS;
    f32x2 px[8], py[8], pz[8], dist[8];
#pragma unroll
    for (int j = 0; j < 8; j++){
      f32x2 x, y, z;
#pragma unroll
      for (int h = 0; h < 2; h++){
        int n = ((2*j + h) << 10) + t;
        x[h] = xb[n];
        y[h] = xb[NPTS + n];
        z[h] = xb[2*NPTS + n];
        xpk[n] = make_float4(x[h], y[h], z[h], 0.f);
      }
      px[j] = x; py[j] = y; pz[j] = z;
      f32x2 big = {1e10f, 1e10f};
      dist[j] = big;
    }
    if (t < 32) ((u64*)sm.fps.warr)[t] = 0ULL;
    const int far0 = finit[b];
    __syncthreads();
    int nbu = far0;
    for (int it = 0; it < NPOINT; it++){
      float4 cc = xpk[nbu];
      if (t == 0){
        out0[((size_t)b*3 + 0)*NPOINT + it] = cc.x;
        out0[((size_t)b*3 + 1)*NPOINT + it] = cc.y;
        out0[((size_t)b*3 + 2)*NPOINT + it] = cc.z;
      }
      float bv = -1.f; int bk = 0;
      {
#pragma clang fp contract(off)
        f32x2 cx2 = {cc.x, cc.x}, cy2 = {cc.y, cc.y}, cz2 = {cc.z, cc.z};
#pragma unroll
        for (int j = 0; j < 8; j++){
          f32x2 dx = px[j] - cx2;
          f32x2 dy = py[j] - cy2;
          f32x2 dz = pz[j] - cz2;
          f32x2 dd = dx*dx + dy*dy + dz*dz;   // matches reference eval order
          f32x2 dm = __builtin_elementwise_min(dist[j], dd);
          dist[j] = dm;
          bool g0 = dm.x > bv;
          bv = g0 ? dm.x : bv;  bk = g0 ? (2*j)   : bk;
          bool g1 = dm.y > bv;
          bv = g1 ? dm.y : bv;  bk = g1 ? (2*j+1) : bk;
        }
      }
      int bi = (bk << 10) + t;
      u64 key = ((u64)__builtin_bit_cast(u32, bv) << 32) | (u64)(u32)(~(u32)bi);
      key = dpp_max<0xB1>(key);   // xor1
      key = dpp_max<0x4E>(key);   // xor2
      key = dpp_max<0x141>(key);  // half_mirror (xor4)
      key = dpp_max<0x140>(key);  // mirror (xor8)
      key = dpp_max<0x142>(key);  // bcast15
      key = dpp_max<0x143>(key);  // bcast31
      if (lane == 63) sm.fps.warr[it & 1][wave] = key;
      __syncthreads();
      u64 kv = sm.fps.warr[it & 1][lane & 15];
      kv = dpp_max<0xB1>(kv);
      kv = dpp_max<0x4E>(kv);
      kv = dpp_max<0x141>(kv);
      kv = dpp_max<0x140>(kv);
      nbu = __builtin_amdgcn_readfirstlane((int)~(u32)kv);
    }
    return;
  }

  // -------------------------------------------------------------- conv path
  const int cb = blockIdx.x - 16;
  const int lw = wave & 3, g = wave >> 2;
  const int Wk = cb*4 + g;
  const int lrow = lane & 15, lq = lane >> 4;
  float* bsum0 = statsF;          float* bsqr0 = statsF + 8192;
  float* bsum1 = statsF + 16384;  float* bsqr1 = statsF + 24576;
  float* bsum2 = statsF + 32768;  float* bsqr2 = statsF + 40960;
  float* a0 = statsF + 49152;       float* d0 = a0 + 128;
  float* a1 = statsF + 49152 + 256; float* d1 = a1 + 128;
  float* a2 = statsF + 49152 + 512; float* d2 = a2 + 128;

  // ---- P0: pack XP + weight prep + zero stat buckets
  for (u32 idx = (u32)cb*1024u + t; idx < 16u*16384u; idx += (u32)NCB*1024u){
    u32 b = idx >> 14, n = idx & 16383u;
    const float* xb = xyz + (size_t)b*3*NPTS + n;
    const float* pb = points + (size_t)b*64*NPTS + n;
    u16* dst = XP + ((size_t)b*NPTS + n)*96;
#pragma unroll
    for (int half = 0; half < 2; half++){
      u32 w[24];
#pragma unroll
      for (int q = 0; q < 24; q++){
        int c0 = half*48 + 2*q, c1 = c0 + 1;
        float f0 = (c0 < 3) ? xb[(size_t)c0*NPTS] : (c0 < 67) ? pb[(size_t)(c0-3)*NPTS] : 0.f;
        float f1 = (c1 < 3) ? xb[(size_t)c1*NPTS] : (c1 < 67) ? pb[(size_t)(c1-3)*NPTS] : 0.f;
        w[q] = (u32)f2bf(f0) | ((u32)f2bf(f1) << 16);
      }
#pragma unroll
      for (int q = 0; q < 6; q++){
        uint4 v; v.x = w[4*q]; v.y = w[4*q+1]; v.z = w[4*q+2]; v.w = w[4*q+3];
        *(uint4*)(dst + half*48 + q*8) = v;
      }
    }
  }
  if (cb == 0){
    for (int i = t; i < 64*96; i += 1024){
      int nn = i / 96, kk = i % 96;
      W0bf[i] = (kk < 67) ? f2bf(W0[nn*67 + kk]) : (u16)0;
    }
    for (int i = t; i < 128*64; i += 1024) W1bf[i] = f2bf(W1[i]);
    for (int i = t; i < 128*128; i += 1024) W2bf[i] = f2bf(W2[i]);
  }
  if (cb == 1){
    for (int i = t; i < 49152; i += 1024) statsF[i] = 0.f;
  }
  __threadfence();
  __syncthreads();
  if (t == 0){ arrive(&ctrs[0]); waitc(&ctrs[0], NCB); }
  __syncthreads();

  // ---- P1: layer 0 (gather + K=96 matmul), stats accumulation
  if (t < 128){ sm.conv.lsum[t] = 0.f; sm.conv.lsqr[t] = 0.f; }
  __syncthreads();
  for (int j2 = Wk; j2 < 4096; j2 += NW){
    const int b = j2 >> 8;
    const size_t srow = (size_t)j2 * 128;
    const int gbase = b*32768 + (j2 & 255)*128;
    const int m0 = lw*32 + lrow, m1 = m0 + 16;
    const int p0 = gidx[gbase + m0];
    const int p1 = gidx[gbase + m1];
    const bf16x8* ar0 = (const bf16x8*)(XP + ((size_t)b*NPTS + p0)*96);
    const bf16x8* ar1 = (const bf16x8*)(XP + ((size_t)b*NPTS + p1)*96);
    f32x4 acc[2][4];
#pragma unroll
    for (int mt = 0; mt < 2; mt++)
#pragma unroll
      for (int nt = 0; nt < 4; nt++){ f32x4 z = {0.f,0.f,0.f,0.f}; acc[mt][nt] = z; }
#pragma unroll
    for (int ks = 0; ks < 3; ks++){
      bf16x8 af0 = ar0[ks*4 + lq];
      bf16x8 af1 = ar1[ks*4 + lq];
#pragma unroll
      for (int nt = 0; nt < 4; nt++){
        bf16x8 bb = *(const bf16x8*)(W0bf + (nt*16 + lrow)*96 + ks*32 + lq*8);
        acc[0][nt] = __builtin_amdgcn_mfma_f32_16x16x32_bf16(af0, bb, acc[0][nt], 0, 0, 0);
        acc[1][nt] = __builtin_amdgcn_mfma_f32_16x16x32_bf16(af1, bb, acc[1][nt], 0, 0, 0);
      }
    }
#pragma unroll
    for (int nt = 0; nt < 4; nt++){
      float s = 0.f, s2 = 0.f;
#pragma unroll
      for (int mt = 0; mt < 2; mt++){
#pragma unroll
        for (int i = 0; i < 4; i++){
          float u = acc[mt][nt][i];
          s += u; s2 = fmaf(u, u, s2);
          int m = lw*32 + mt*16 + lq*4 + i;
          y0[(srow + m)*64 + nt*16 + lrow] = f2bf(u);
        }
      }
      s  += __shfl_xor(s, 16, 64);  s  += __shfl_xor(s, 32, 64);
      s2 += __shfl_xor(s2, 16, 64); s2 += __shfl_xor(s2, 32, 64);
      if (lane < 16){ atomicAdd(&sm.conv.lsum[nt*16 + lane], s); atomicAdd(&sm.conv.lsqr[nt*16 + lane], s2); }
    }
  }
  __syncthreads();
  if (t < 64){
    atomicAdd(&bsum0[(cb & 63)*128 + t], sm.conv.lsum[t]);
    atomicAdd(&bsqr0[(cb & 63)*128 + t], sm.conv.lsqr[t]);
  }
  __threadfence();
  __syncthreads();
  if (t == 0) arrive(&ctrs[1]);
  if (cb == 0){
    if (t == 0) waitc(&ctrs[1], NCB);
    __syncthreads();
    if (t < 64){
      float s = 0.f, s2 = 0.f;
      for (int k = 0; k < 64; k++){ s += bsum0[k*128 + t]; s2 += bsqr0[k*128 + t]; }
      const float inv = 1.f / (float)STOT;
      float m = s * inv, v = s2 * inv - m*m;
      float aa = g0v[t] / sqrtf(v + 1e-5f);
      a0[t] = aa; d0[t] = be0[t] - m*aa;
    }
    __threadfence();
    __syncthreads();
    if (t == 0) arrive(&ctrs[2]);
  }
  if (t == 0) waitc(&ctrs[2], 1);
  __syncthreads();

  // ---- P2: layer 1 (K=64 -> 128)
  if (t < 128){ sm.conv.lsum[t] = 0.f; sm.conv.lsqr[t] = 0.f; }
  if (t < 64){ sm.conv.av[t] = a0[t]; sm.conv.dv[t] = d0[t]; }
  __syncthreads();
  for (int j2 = Wk; j2 < 4096; j2 += NW){
    const size_t srow = (size_t)j2 * 128;
    const int m0 = lw*32 + lrow, m1 = m0 + 16;
    const u16* row0 = y0 + (srow + m0)*64;
    const u16* row1 = y0 + (srow + m1)*64;
    f32x4 acc[2][8];
#pragma unroll
    for (int mt = 0; mt < 2; mt++)
#pragma unroll
      for (int nt = 0; nt < 8; nt++){ f32x4 z = {0.f,0.f,0.f,0.f}; acc[mt][nt] = z; }
#pragma unroll
    for (int ks = 0; ks < 2; ks++){
      const int ko = ks*32 + lq*8;
      bf16x8 af0 = load_bn_relu(row0, ko, sm.conv.av, sm.conv.dv);
      bf16x8 af1 = load_bn_relu(row1, ko, sm.conv.av, sm.conv.dv);
#pragma unroll
      for (int nt = 0; nt < 8; nt++){
        bf16x8 bb = *(const bf16x8*)(W1bf + (nt*16 + lrow)*64 + ko);
        acc[0][nt] = __builtin_amdgcn_mfma_f32_16x16x32_bf16(af0, bb, acc[0][nt], 0, 0, 0);
        acc[1][nt] = __builtin_amdgcn_mfma_f32_16x16x32_bf16(af1, bb, acc[1][nt], 0, 0, 0);
      }
    }
#pragma unroll
    for (int nt = 0; nt < 8; nt++){
      float s = 0.f, s2 = 0.f;
#pragma unroll
      for (int mt = 0; mt < 2; mt++){
#pragma unroll
        for (int i = 0; i < 4; i++){
          float u = acc[mt][nt][i];
          s += u; s2 = fmaf(u, u, s2);
          int m = lw*32 + mt*16 + lq*4 + i;
          y1[(srow + m)*128 + nt*16 + lrow] = f2bf(u);
        }
      }
      s  += __shfl_xor(s, 16, 64);  s  += __shfl_xor(s, 32, 64);
      s2 += __shfl_xor(s2, 16, 64); s2 += __shfl_xor(s2, 32, 64);
      if (lane < 16){ atomicAdd(&sm.conv.lsum[nt*16 + lane], s); atomicAdd(&sm.conv.lsqr[nt*16 + lane], s2); }
    }
  }
  __syncthreads();
  if (t < 128){
    atomicAdd(&bsum1[(cb & 63)*128 + t], sm.conv.lsum[t]);
    atomicAdd(&bsqr1[(cb & 63)*128 + t], sm.conv.lsqr[t]);
  }
  __threadfence();
  __syncthreads();
  if (t == 0) arrive(&ctrs[3]);
  if (cb == 0){
    if (t == 0) waitc(&ctrs[3], NCB);
    __syncthreads();
    if (t < 128){
      float s = 0.f, s2 = 0.f;
      for (int k = 0; k < 64; k++){ s += bsum1[k*128 + t]; s2 += bsqr1[k*128 + t]; }
      const float inv = 1.f / (float)STOT;
      float m = s * inv, v = s2 * inv - m*m;
      float aa = g1v[t] / sqrtf(v + 1e-5f);
      a1[t] = aa; d1[t] = be1[t] - m*aa;
    }
    __threadfence();
    __syncthreads();
    if (t == 0) arrive(&ctrs[4]);
  }
  if (t == 0) waitc(&ctrs[4], 1);
  __syncthreads();

  // ---- P3: layer 2 (K=128 -> 128) + per-group max/min of pre-BN y2
  if (t < 128){ sm.conv.lsum[t] = 0.f; sm.conv.lsqr[t] = 0.f;
                sm.conv.av[t] = a1[t]; sm.conv.dv[t] = d1[t]; }
  __syncthreads();
  for (int j2 = Wk; j2 < 4096; j2 += NW){
    const size_t srow = (size_t)j2 * 128;
    const int m0 = lw*32 + lrow, m1 = m0 + 16;
    const u16* row0 = y1 + (srow + m0)*128;
    const u16* row1 = y1 + (srow + m1)*128;
    f32x4 acc[2][8];
#pragma unroll
    for (int mt = 0; mt < 2; mt++)
#pragma unroll
      for (int nt = 0; nt < 8; nt++){ f32x4 z = {0.f,0.f,0.f,0.f}; acc[mt][nt] = z; }
#pragma unroll
    for (int ks = 0; ks < 4; ks++){
      const int ko = ks*32 + lq*8;
      bf16x8 af0 = load_bn_relu(row0, ko, sm.conv.av, sm.conv.dv);
      bf16x8 af1 = load_bn_relu(row1, ko, sm.conv.av, sm.conv.dv);
#pragma unroll
      for (int nt = 0; nt < 8; nt++){
        bf16x8 bb = *(const bf16x8*)(W2bf + (nt*16 + lrow)*128 + ko);
        acc[0][nt] = __builtin_amdgcn_mfma_f32_16x16x32_bf16(af0, bb, acc[0][nt], 0, 0, 0);
        acc[1][nt] = __builtin_amdgcn_mfma_f32_16x16x32_bf16(af1, bb, acc[1][nt], 0, 0, 0);
      }
    }
#pragma unroll
    for (int nt = 0; nt < 8; nt++){
      float s = 0.f, s2 = 0.f, mx = -3.4e38f, mn = 3.4e38f;
#pragma unroll
      for (int mt = 0; mt < 2; mt++){
#pragma unroll
        for (int i = 0; i < 4; i++){
          float u = acc[mt][nt][i];
          s += u; s2 = fmaf(u, u, s2);
          mx = fmaxf(mx, u); mn = fminf(mn, u);
        }
      }
      s  += __shfl_xor(s, 16, 64);  s  += __shfl_xor(s, 32, 64);
      s2 += __shfl_xor(s2, 16, 64); s2 += __shfl_xor(s2, 32, 64);
      mx = fmaxf(mx, __shfl_xor(mx, 16, 64)); mx = fmaxf(mx, __shfl_xor(mx, 32, 64));
      mn = fminf(mn, __shfl_xor(mn, 16, 64)); mn = fminf(mn, __shfl_xor(mn, 32, 64));
      if (lane < 16){
        size_t gi = ((size_t)j2*4 + lw)*128 + nt*16 + lane;
        maxb[gi] = mx; minb[gi] = mn;
        atomicAdd(&sm.conv.lsum[nt*16 + lane], s); atomicAdd(&sm.conv.lsqr[nt*16 + lane], s2);
      }
    }
  }
  __syncthreads();
  if (t < 128){
    atomicAdd(&bsum2[(cb & 63)*128 + t], sm.conv.lsum[t]);
    atomicAdd(&bsqr2[(cb & 63)*128 + t], sm.conv.lsqr[t]);
  }
  __threadfence();
  __syncthreads();
  if (t == 0) arrive(&ctrs[5]);
  if (cb == 0){
    if (t == 0) waitc(&ctrs[5], NCB);
    __syncthreads();
    if (t < 128){
      float s = 0.f, s2 = 0.f;
      for (int k = 0; k < 64; k++){ s += bsum2[k*128 + t]; s2 += bsqr2[k*128 + t]; }
      const float inv = 1.f / (float)STOT;
      float m = s * inv, v = s2 * inv - m*m;
      float aa = g2v[t] / sqrtf(v + 1e-5f);
      a2[t] = aa; d2[t] = be2[t] - m*aa;
    }
    __threadfence();
    __syncthreads();
    if (t == 0) arrive(&ctrs[6]);
  }
  if (t == 0) waitc(&ctrs[6], 1);
  __syncthreads();

  // ---- P4: final BN2+relu on group max/min, store [B,128,NP] (np coalesced)
  for (u32 e = (u32)cb*1024u + t; e < 16u*1024u*128u; e += (u32)NCB*1024u){
    u32 np = e & 1023u;
    u32 c  = (e >> 10) & 127u;
    u32 b  = e >> 17;
    size_t gi = ((size_t)b*1024 + np)*128 + c;
    float a = a2[c];
    float v = (a >= 0.f) ? maxb[gi] : minb[gi];
    out1[((size_t)b*128 + c)*1024 + np] = fmaxf(fmaf(a, v, d2[c]), 0.f);
  }
}

// ---------------------------------------------------------------- launch
extern "C" void kernel_launch(void* const* d_in, const int* in_sizes, int n_in,
                              void* d_out, int out_size, void* d_ws, size_t ws_size,
                              hipStream_t stream) {
  const float* xyz    = (const float*)d_in[0];
  const float* points = (const float*)d_in[1];
  const int*   finit  = (const int*)d_in[2];
  const int*   gidx   = (const int*)d_in[3];
  const float* W0  = (const float*)d_in[4];
  const float* g0v = (const float*)d_in[6];
  const float* be0 = (const float*)d_in[7];
  const float* W1  = (const float*)d_in[8];
  const float* g1v = (const float*)d_in[10];
  const float* be1 = (const float*)d_in[11];
  const float* W2  = (const float*)d_in[12];
  const float* g2v = (const float*)d_in[14];
  const float* be2 = (const float*)d_in[15];

  float* out0 = (float*)d_out;
  float* out1 = out0 + 16*3*NPOINT;   // 49152

  char* ws = (char*)d_ws;
  // layout (bytes):
  //   [0, 128M)            y1 (l1 out); XP aliases [0,48M) (dead before l1 writes)
  //   [128M, 192M)         y0 (l0 out); maxb/minb alias (y0 dead after l1)
  //   [192M, +196.6K)      statsF (bsum/bsqr/a/d)
  //   then W0bf/W1bf/W2bf, xpk (4M), ctrs
  u16* y1 = (u16*)ws;
  u16* XP = (u16*)ws;
  u16* y0 = (u16*)(ws + 134217728);
  float* maxb = (float*)(ws + 134217728);
  float* minb = (float*)(ws + 134217728 + 8388608);
  float* statsF = (float*)(ws + 201326592);
  u16* W0bf = (u16*)(ws + 201326592 + 49920*4);          // 201526272
  u16* W1bf = W0bf + 64*96;
  u16* W2bf = W1bf + 128*64;
  float4* xpk = (float4*)(ws + 201587712);               // 4 MiB
  u32* ctrs = (u32*)(ws + 205782016);                    // 64 u32

  zero_kernel<<<1, 64, 0, stream>>>(ctrs);
  mega_kernel<<<256, 1024, 0, stream>>>(
      xyz, points, finit, gidx,
      W0, g0v, be0, W1, g1v, be1, W2, g2v, be2,
      out0, out1, XP, y0, y1, maxb, minb, statsF, xpk,
      W0bf, W1bf, W2bf, ctrs);
}

// Round 7
// 1910.425 us; speedup vs baseline: 1.4147x; 1.3103x over previous
//
#include <hip/hip_runtime.h>

typedef short bf16x8 __attribute__((ext_vector_type(8)));
typedef float f32x4 __attribute__((ext_vector_type(4)));
typedef float f32x2 __attribute__((ext_vector_type(2)));
typedef unsigned short u16;
typedef unsigned int u32;
typedef unsigned long long u64;

#define NPTS 16384
#define NPOINT 1024
#define STOT 524288   // 16*1024*32 samples
#define NCB 240       // conv blocks (blocks 16..255)
#define NW  960       // conv workers (4-wave groups)

__device__ __forceinline__ u16 f2bf(float f){
  u32 u = __builtin_bit_cast(u32, f);
  u += 0x7fffu + ((u >> 16) & 1u);
  return (u16)(u >> 16);
}
__device__ __forceinline__ float bf2f(u16 u){
  u32 x = ((u32)u) << 16;
  return __builtin_bit_cast(float, x);
}

// f32 max-combine across lanes via DPP (1-2 VALU insts per level).
template<int CTRL>
__device__ __forceinline__ float dpp_maxf(float v){
  int x = __builtin_amdgcn_update_dpp(0, __builtin_bit_cast(int, v), CTRL, 0xf, 0xf, true);
  return fmaxf(v, __builtin_bit_cast(float, x));
}
// 64-bit max-combine across lanes via DPP (exact-tie fallback path).
template<int CTRL>
__device__ __forceinline__ u64 dpp_max(u64 key){
  u32 lo = (u32)key, hi = (u32)(key >> 32);
  u32 lo1 = (u32)__builtin_amdgcn_update_dpp(0, (int)lo, CTRL, 0xf, 0xf, true);
  u32 hi1 = (u32)__builtin_amdgcn_update_dpp(0, (int)hi, CTRL, 0xf, 0xf, true);
  u64 k1 = ((u64)hi1 << 32) | (u64)lo1;
  return (k1 > key) ? k1 : key;
}
__device__ __forceinline__ u64 packkey(float d, int idx){
  // d >= 0 so uint order on float bits == float order; ~idx -> ties pick smaller idx
  return ((u64)__builtin_bit_cast(u32, d) << 32) | (u64)(u32)(~(u32)idx);
}

__device__ __forceinline__ void arrive(u32* c){
  __hip_atomic_fetch_add(c, 1u, __ATOMIC_RELEASE, __HIP_MEMORY_SCOPE_AGENT);
}
__device__ __forceinline__ void waitc(u32* c, u32 tgt){
  while (__hip_atomic_load(c, __ATOMIC_ACQUIRE, __HIP_MEMORY_SCOPE_AGENT) < tgt)
    __builtin_amdgcn_s_sleep(16);
}

struct FpsS  { uint2 wkey[2][16]; float4 csl[2]; };
struct ConvS { float lsum[128]; float lsqr[128]; float av[128]; float dv[128]; };
union SMemU  { FpsS fps; ConvS conv; };

__device__ __forceinline__ bf16x8 load_bn_relu(const u16* __restrict__ row, int ko,
                                               const float* __restrict__ av,
                                               const float* __restrict__ dv){
  uint4 r = *(const uint4*)(row + ko);
  u32 w[4] = {r.x, r.y, r.z, r.w};
  bf16x8 out;
#pragma unroll
  for (int jj = 0; jj < 8; jj++){
    u16 us = (u16)(w[jj >> 1] >> ((jj & 1) * 16));
    float h = fmaxf(fmaf(av[ko + jj], bf2f(us), dv[ko + jj]), 0.f);
    out[jj] = (short)f2bf(h);
  }
  return out;
}

// zero the sync counters (ws is re-poisoned 0xAA before every call)
__global__ void zero_kernel(u32* __restrict__ ctrs){
  if (threadIdx.x < 64) ctrs[threadIdx.x] = 0;
}

// ================================================================ MEGA KERNEL
// blocks 0..15  : FPS — all state in registers+LDS, ZERO global memory in the
//                 iter loop (out0 store is fire-and-forget). Argmax: per-wave
//                 f32 DPP max + ballot/ctz/readlane index recovery (exact-tie
//                 fallback = u64 DPP chain); stage2 over 16 (max,idx) pairs.
//                 Owner thread writes winner coords to ping-pong LDS center.
// blocks 16..255: persistent conv chain (phases via device-scope counters).
// launch_bounds(1024,4): 128-VGPR cap -> NO spills (fps arrays ~100 VGPR).
__global__ __launch_bounds__(1024, 4) void mega_kernel(
    const float* __restrict__ xyz, const float* __restrict__ points,
    const int* __restrict__ finit, const int* __restrict__ gidx,
    const float* __restrict__ W0, const float* __restrict__ g0v, const float* __restrict__ be0,
    const float* __restrict__ W1, const float* __restrict__ g1v, const float* __restrict__ be1,
    const float* __restrict__ W2, const float* __restrict__ g2v, const float* __restrict__ be2,
    float* __restrict__ out0, float* __restrict__ out1,
    u16* __restrict__ XP, u16* __restrict__ y0, u16* __restrict__ y1,
    float* __restrict__ maxb, float* __restrict__ minb,
    float* __restrict__ statsF,
    u16* __restrict__ W0bf, u16* __restrict__ W1bf, u16* __restrict__ W2bf,
    u32* __restrict__ ctrs){
  __shared__ SMemU sm;
  const int t = threadIdx.x;
  const int wave = t >> 6, lane = t & 63;

  if (blockIdx.x < 16){
    // ------------------------------------------------------------ FPS path
    const int b = blockIdx.x;
    const float* xb = xyz + (size_t)b * 3 * NPTS;
    f32x2 px[8], py[8], pz[8], dist[8];
#pragma unroll
    for (int j = 0; j < 8; j++){
      f32x2 x, y, z;
#pragma unroll
      for (int h = 0; h < 2; h++){
        int n = ((2*j + h) << 10) + t;
        x[h] = xb[n];
        y[h] = xb[NPTS + n];
        z[h] = xb[2*NPTS + n];
      }
      px[j] = x; py[j] = y; pz[j] = z;
      f32x2 big = {1e10f, 1e10f};
      dist[j] = big;
    }
    const int far0 = finit[b];
    if (t == (far0 & 1023)){
      int kk = far0 >> 10;
      float sx = px[0].x, sy = py[0].x, sz = pz[0].x;
#pragma unroll
      for (int k = 1; k < 16; k++){
        bool e = (kk == k);
        float vx = px[k>>1][k&1], vy = py[k>>1][k&1], vz = pz[k>>1][k&1];
        sx = e ? vx : sx; sy = e ? vy : sy; sz = e ? vz : sz;
      }
      sm.fps.csl[0] = make_float4(sx, sy, sz, 0.f);
    }
    __syncthreads();
    for (int it = 0; it < NPOINT; it++){
      const int p = it & 1;
      float4 cc = sm.fps.csl[p];       // LDS broadcast, no global access
      if (t == 0){
        out0[((size_t)b*3 + 0)*NPOINT + it] = cc.x;
        out0[((size_t)b*3 + 1)*NPOINT + it] = cc.y;
        out0[((size_t)b*3 + 2)*NPOINT + it] = cc.z;
      }
      float bv = -1.f; int bk = 0;
      {
#pragma clang fp contract(off)
        f32x2 cx2 = {cc.x, cc.x}, cy2 = {cc.y, cc.y}, cz2 = {cc.z, cc.z};
#pragma unroll
        for (int j = 0; j < 8; j++){
          f32x2 dx = px[j] - cx2;
          f32x2 dy = py[j] - cy2;
          f32x2 dz = pz[j] - cz2;
          f32x2 dd = dx*dx + dy*dy + dz*dz;   // matches reference eval order
          f32x2 dm = __builtin_elementwise_min(dist[j], dd);
          dist[j] = dm;
          bool g0 = dm.x > bv;
          bv = g0 ? dm.x : bv;  bk = g0 ? (2*j)   : bk;
          bool g1 = dm.y > bv;
          bv = g1 ? dm.y : bv;  bk = g1 ? (2*j+1) : bk;
        }
      }
      // ---- stage 1: wave max (f32 DPP) + index recovery via ballot
      float m = bv;
      m = dpp_maxf<0xB1>(m);   // xor1
      m = dpp_maxf<0x4E>(m);   // xor2
      m = dpp_maxf<0x141>(m);  // half_mirror (xor4)
      m = dpp_maxf<0x140>(m);  // mirror (xor8)
      m = dpp_maxf<0x142>(m);  // bcast15
      m = dpp_maxf<0x143>(m);  // bcast31 -> lanes 48-63 hold wave max
      float ms = __builtin_bit_cast(float, __builtin_amdgcn_readlane(__builtin_bit_cast(int, m), 63));
      u64 mk = __ballot(bv == ms);
      u32 widx;
      if (__popcll(mk) == 1){
        int L = (int)__builtin_ctzll(mk);
        int kwin = __builtin_amdgcn_readlane(bk, L);
        widx = (u32)((kwin << 10) + (wave << 6) + L);
      } else {
        // exact-tie fallback: full u64 (dist,~idx) DPP chain
        u64 key = packkey(bv, (bk << 10) + t);
        key = dpp_max<0xB1>(key); key = dpp_max<0x4E>(key);
        key = dpp_max<0x141>(key); key = dpp_max<0x140>(key);
        key = dpp_max<0x142>(key); key = dpp_max<0x143>(key);
        u32 lo = (u32)__builtin_amdgcn_readlane((int)(u32)key, 63);
        widx = ~lo;
      }
      if (lane == 0){
        uint2 wk; wk.x = widx; wk.y = __builtin_bit_cast(u32, ms);
        sm.fps.wkey[p][wave] = wk;
      }
      __syncthreads();                 // B1
      // ---- stage 2: reduce 16 wave keys
      uint2 wk = sm.fps.wkey[p][lane & 15];
      float wv = __builtin_bit_cast(float, wk.y);
      float g4 = wv;
      g4 = dpp_maxf<0xB1>(g4); g4 = dpp_maxf<0x4E>(g4);
      g4 = dpp_maxf<0x141>(g4); g4 = dpp_maxf<0x140>(g4);  // all lanes: global max
      float gms = __builtin_bit_cast(float, __builtin_amdgcn_readfirstlane(__builtin_bit_cast(int, g4)));
      u64 mk2 = __ballot(wv == gms);
      u32 lo16 = (u32)mk2 & 0xFFFFu;
      int nb;
      if (__popc(lo16) == 1){
        int w = (int)__builtin_ctz(lo16);
        nb = __builtin_amdgcn_readlane((int)wk.x, w);
      } else {
        u64 k2 = ((u64)wk.y << 32) | (u64)(u32)(~wk.x);
        k2 = dpp_max<0xB1>(k2); k2 = dpp_max<0x4E>(k2);
        k2 = dpp_max<0x141>(k2); k2 = dpp_max<0x140>(k2);
        u32 lo = (u32)__builtin_amdgcn_readfirstlane((int)(u32)k2);
        nb = (int)~lo;
      }
      nb = __builtin_amdgcn_readfirstlane(nb);
      // ---- owner publishes next center to the other parity slot
      if (t == (nb & 1023)){
        int kk = nb >> 10;
        float sx = px[0].x, sy = py[0].x, sz = pz[0].x;
#pragma unroll
        for (int k = 1; k < 16; k++){
          bool e = (kk == k);
          float vx = px[k>>1][k&1], vy = py[k>>1][k&1], vz = pz[k>>1][k&1];
          sx = e ? vx : sx; sy = e ? vy : sy; sz = e ? vz : sz;
        }
        sm.fps.csl[p ^ 1] = make_float4(sx, sy, sz, 0.f);
      }
      __syncthreads();                 // B2
    }
    return;
  }

  // -------------------------------------------------------------- conv path
  const int cb = blockIdx.x - 16;
  const int lw = wave & 3, g = wave >> 2;
  const int Wk = cb*4 + g;
  const int lrow = lane & 15, lq = lane >> 4;
  float* bsum0 = statsF;          float* bsqr0 = statsF + 8192;
  float* bsum1 = statsF + 16384;  float* bsqr1 = statsF + 24576;
  float* bsum2 = statsF + 32768;  float* bsqr2 = statsF + 40960;
  float* a0 = statsF + 49152;       float* d0 = a0 + 128;
  float* a1 = statsF + 49152 + 256; float* d1 = a1 + 128;
  float* a2 = statsF + 49152 + 512; float* d2 = a2 + 128;

  // ---- P0: pack XP + weight prep + zero stat buckets
  for (u32 idx = (u32)cb*1024u + t; idx < 16u*16384u; idx += (u32)NCB*1024u){
    u32 b = idx >> 14, n = idx & 16383u;
    const float* xb = xyz + (size_t)b*3*NPTS + n;
    const float* pb = points + (size_t)b*64*NPTS + n;
    u16* dst = XP + ((size_t)b*NPTS + n)*96;
#pragma unroll
    for (int half = 0; half < 2; half++){
      u32 w[24];
#pragma unroll
      for (int q = 0; q < 24; q++){
        int c0 = half*48 + 2*q, c1 = c0 + 1;
        float f0 = (c0 < 3) ? xb[(size_t)c0*NPTS] : (c0 < 67) ? pb[(size_t)(c0-3)*NPTS] : 0.f;
        float f1 = (c1 < 3) ? xb[(size_t)c1*NPTS] : (c1 < 67) ? pb[(size_t)(c1-3)*NPTS] : 0.f;
        w[q] = (u32)f2bf(f0) | ((u32)f2bf(f1) << 16);
      }
#pragma unroll
      for (int q = 0; q < 6; q++){
        uint4 v; v.x = w[4*q]; v.y = w[4*q+1]; v.z = w[4*q+2]; v.w = w[4*q+3];
        *(uint4*)(dst + half*48 + q*8) = v;
      }
    }
  }
  if (cb == 0){
    for (int i = t; i < 64*96; i += 1024){
      int nn = i / 96, kk = i % 96;
      W0bf[i] = (kk < 67) ? f2bf(W0[nn*67 + kk]) : (u16)0;
    }
    for (int i = t; i < 128*64; i += 1024) W1bf[i] = f2bf(W1[i]);
    for (int i = t; i < 128*128; i += 1024) W2bf[i] = f2bf(W2[i]);
  }
  if (cb == 1){
    for (int i = t; i < 49152; i += 1024) statsF[i] = 0.f;
  }
  __threadfence();
  __syncthreads();
  if (t == 0){ arrive(&ctrs[0]); waitc(&ctrs[0], NCB); }
  __syncthreads();

  // ---- P1: layer 0 (gather + K=96 matmul), stats accumulation
  if (t < 128){ sm.conv.lsum[t] = 0.f; sm.conv.lsqr[t] = 0.f; }
  __syncthreads();
  for (int j2 = Wk; j2 < 4096; j2 += NW){
    const int b = j2 >> 8;
    const size_t srow = (size_t)j2 * 128;
    const int gbase = b*32768 + (j2 & 255)*128;
    const int m0 = lw*32 + lrow, m1 = m0 + 16;
    const int p0 = gidx[gbase + m0];
    const int p1 = gidx[gbase + m1];
    const bf16x8* ar0 = (const bf16x8*)(XP + ((size_t)b*NPTS + p0)*96);
    const bf16x8* ar1 = (const bf16x8*)(XP + ((size_t)b*NPTS + p1)*96);
    f32x4 acc[2][4];
#pragma unroll
    for (int mt = 0; mt < 2; mt++)
#pragma unroll
      for (int nt = 0; nt < 4; nt++){ f32x4 z = {0.f,0.f,0.f,0.f}; acc[mt][nt] = z; }
#pragma unroll
    for (int ks = 0; ks < 3; ks++){
      bf16x8 af0 = ar0[ks*4 + lq];
      bf16x8 af1 = ar1[ks*4 + lq];
#pragma unroll
      for (int nt = 0; nt < 4; nt++){
        bf16x8 bb = *(const bf16x8*)(W0bf + (nt*16 + lrow)*96 + ks*32 + lq*8);
        acc[0][nt] = __builtin_amdgcn_mfma_f32_16x16x32_bf16(af0, bb, acc[0][nt], 0, 0, 0);
        acc[1][nt] = __builtin_amdgcn_mfma_f32_16x16x32_bf16(af1, bb, acc[1][nt], 0, 0, 0);
      }
    }
#pragma unroll
    for (int nt = 0; nt < 4; nt++){
      float s = 0.f, s2 = 0.f;
#pragma unroll
      for (int mt = 0; mt < 2; mt++){
#pragma unroll
        for (int i = 0; i < 4; i++){
          float u = acc[mt][nt][i];
          s += u; s2 = fmaf(u, u, s2);
          int m = lw*32 + mt*16 + lq*4 + i;
          y0[(srow + m)*64 + nt*16 + lrow] = f2bf(u);
        }
      }
      s  += __shfl_xor(s, 16, 64);  s  += __shfl_xor(s, 32, 64);
      s2 += __shfl_xor(s2, 16, 64); s2 += __shfl_xor(s2, 32, 64);
      if (lane < 16){ atomicAdd(&sm.conv.lsum[nt*16 + lane], s); atomicAdd(&sm.conv.lsqr[nt*16 + lane], s2); }
    }
  }
  __syncthreads();
  if (t < 64){
    atomicAdd(&bsum0[(cb & 63)*128 + t], sm.conv.lsum[t]);
    atomicAdd(&bsqr0[(cb & 63)*128 + t], sm.conv.lsqr[t]);
  }
  __threadfence();
  __syncthreads();
  if (t == 0) arrive(&ctrs[1]);
  if (cb == 0){
    if (t == 0) waitc(&ctrs[1], NCB);
    __syncthreads();
    if (t < 64){
      float s = 0.f, s2 = 0.f;
      for (int k = 0; k < 64; k++){ s += bsum0[k*128 + t]; s2 += bsqr0[k*128 + t]; }
      const float inv = 1.f / (float)STOT;
      float m = s * inv, v = s2 * inv - m*m;
      float aa = g0v[t] / sqrtf(v + 1e-5f);
      a0[t] = aa; d0[t] = be0[t] - m*aa;
    }
    __threadfence();
    __syncthreads();
    if (t == 0) arrive(&ctrs[2]);
  }
  if (t == 0) waitc(&ctrs[2], 1);
  __syncthreads();

  // ---- P2: layer 1 (K=64 -> 128)
  if (t < 128){ sm.conv.lsum[t] = 0.f; sm.conv.lsqr[t] = 0.f; }
  if (t < 64){ sm.conv.av[t] = a0[t]; sm.conv.dv[t] = d0[t]; }
  __syncthreads();
  for (int j2 = Wk; j2 < 4096; j2 += NW){
    const size_t srow = (size_t)j2 * 128;
    const int m0 = lw*32 + lrow, m1 = m0 + 16;
    const u16* row0 = y0 + (srow + m0)*64;
    const u16* row1 = y0 + (srow + m1)*64;
    f32x4 acc[2][8];
#pragma unroll
    for (int mt = 0; mt < 2; mt++)
#pragma unroll
      for (int nt = 0; nt < 8; nt++){ f32x4 z = {0.f,0.f,0.f,0.f}; acc[mt][nt] = z; }
#pragma unroll
    for (int ks = 0; ks < 2; ks++){
      const int ko = ks*32 + lq*8;
      bf16x8 af0 = load_bn_relu(row0, ko, sm.conv.av, sm.conv.dv);
      bf16x8 af1 = load_bn_relu(row1, ko, sm.conv.av, sm.conv.dv);
#pragma unroll
      for (int nt = 0; nt < 8; nt++){
        bf16x8 bb = *(const bf16x8*)(W1bf + (nt*16 + lrow)*64 + ko);
        acc[0][nt] = __builtin_amdgcn_mfma_f32_16x16x32_bf16(af0, bb, acc[0][nt], 0, 0, 0);
        acc[1][nt] = __builtin_amdgcn_mfma_f32_16x16x32_bf16(af1, bb, acc[1][nt], 0, 0, 0);
      }
    }
#pragma unroll
    for (int nt = 0; nt < 8; nt++){
      float s = 0.f, s2 = 0.f;
#pragma unroll
      for (int mt = 0; mt < 2; mt++){
#pragma unroll
        for (int i = 0; i < 4; i++){
          float u = acc[mt][nt][i];
          s += u; s2 = fmaf(u, u, s2);
          int m = lw*32 + mt*16 + lq*4 + i;
          y1[(srow + m)*128 + nt*16 + lrow] = f2bf(u);
        }
      }
      s  += __shfl_xor(s, 16, 64);  s  += __shfl_xor(s, 32, 64);
      s2 += __shfl_xor(s2, 16, 64); s2 += __shfl_xor(s2, 32, 64);
      if (lane < 16){ atomicAdd(&sm.conv.lsum[nt*16 + lane], s); atomicAdd(&sm.conv.lsqr[nt*16 + lane], s2); }
    }
  }
  __syncthreads();
  if (t < 128){
    atomicAdd(&bsum1[(cb & 63)*128 + t], sm.conv.lsum[t]);
    atomicAdd(&bsqr1[(cb & 63)*128 + t], sm.conv.lsqr[t]);
  }
  __threadfence();
  __syncthreads();
  if (t == 0) arrive(&ctrs[3]);
  if (cb == 0){
    if (t == 0) waitc(&ctrs[3], NCB);
    __syncthreads();
    if (t < 128){
      float s = 0.f, s2 = 0.f;
      for (int k = 0; k < 64; k++){ s += bsum1[k*128 + t]; s2 += bsqr1[k*128 + t]; }
      const float inv = 1.f / (float)STOT;
      float m = s * inv, v = s2 * inv - m*m;
      float aa = g1v[t] / sqrtf(v + 1e-5f);
      a1[t] = aa; d1[t] = be1[t] - m*aa;
    }
    __threadfence();
    __syncthreads();
    if (t == 0) arrive(&ctrs[4]);
  }
  if (t == 0) waitc(&ctrs[4], 1);
  __syncthreads();

  // ---- P3: layer 2 (K=128 -> 128) + per-group max/min of pre-BN y2
  if (t < 128){ sm.conv.lsum[t] = 0.f; sm.conv.lsqr[t] = 0.f;
                sm.conv.av[t] = a1[t]; sm.conv.dv[t] = d1[t]; }
  __syncthreads();
  for (int j2 = Wk; j2 < 4096; j2 += NW){
    const size_t srow = (size_t)j2 * 128;
    const int m0 = lw*32 + lrow, m1 = m0 + 16;
    const u16* row0 = y1 + (srow + m0)*128;
    const u16* row1 = y1 + (srow + m1)*128;
    f32x4 acc[2][8];
#pragma unroll
    for (int mt = 0; mt < 2; mt++)
#pragma unroll
      for (int nt = 0; nt < 8; nt++){ f32x4 z = {0.f,0.f,0.f,0.f}; acc[mt][nt] = z; }
#pragma unroll
    for (int ks = 0; ks < 4; ks++){
      const int ko = ks*32 + lq*8;
      bf16x8 af0 = load_bn_relu(row0, ko, sm.conv.av, sm.conv.dv);
      bf16x8 af1 = load_bn_relu(row1, ko, sm.conv.av, sm.conv.dv);
#pragma unroll
      for (int nt = 0; nt < 8; nt++){
        bf16x8 bb = *(const bf16x8*)(W2bf + (nt*16 + lrow)*128 + ko);
        acc[0][nt] = __builtin_amdgcn_mfma_f32_16x16x32_bf16(af0, bb, acc[0][nt], 0, 0, 0);
        acc[1][nt] = __builtin_amdgcn_mfma_f32_16x16x32_bf16(af1, bb, acc[1][nt], 0, 0, 0);
      }
    }
#pragma unroll
    for (int nt = 0; nt < 8; nt++){
      float s = 0.f, s2 = 0.f, mx = -3.4e38f, mn = 3.4e38f;
#pragma unroll
      for (int mt = 0; mt < 2; mt++){
#pragma unroll
        for (int i = 0; i < 4; i++){
          float u = acc[mt][nt][i];
          s += u; s2 = fmaf(u, u, s2);
          mx = fmaxf(mx, u); mn = fminf(mn, u);
        }
      }
      s  += __shfl_xor(s, 16, 64);  s  += __shfl_xor(s, 32, 64);
      s2 += __shfl_xor(s2, 16, 64); s2 += __shfl_xor(s2, 32, 64);
      mx = fmaxf(mx, __shfl_xor(mx, 16, 64)); mx = fmaxf(mx, __shfl_xor(mx, 32, 64));
      mn = fminf(mn, __shfl_xor(mn, 16, 64)); mn = fminf(mn, __shfl_xor(mn, 32, 64));
      if (lane < 16){
        size_t gi = ((size_t)j2*4 + lw)*128 + nt*16 + lane;
        maxb[gi] = mx; minb[gi] = mn;
        atomicAdd(&sm.conv.lsum[nt*16 + lane], s); atomicAdd(&sm.conv.lsqr[nt*16 + lane], s2);
      }
    }
  }
  __syncthreads();
  if (t < 128){
    atomicAdd(&bsum2[(cb & 63)*128 + t], sm.conv.lsum[t]);
    atomicAdd(&bsqr2[(cb & 63)*128 + t], sm.conv.lsqr[t]);
  }
  __threadfence();
  __syncthreads();
  if (t == 0) arrive(&ctrs[5]);
  if (cb == 0){
    if (t == 0) waitc(&ctrs[5], NCB);
    __syncthreads();
    if (t < 128){
      float s = 0.f, s2 = 0.f;
      for (int k = 0; k < 64; k++){ s += bsum2[k*128 + t]; s2 += bsqr2[k*128 + t]; }
      const float inv = 1.f / (float)STOT;
      float m = s * inv, v = s2 * inv - m*m;
      float aa = g2v[t] / sqrtf(v + 1e-5f);
      a2[t] = aa; d2[t] = be2[t] - m*aa;
    }
    __threadfence();
    __syncthreads();
    if (t == 0) arrive(&ctrs[6]);
  }
  if (t == 0) waitc(&ctrs[6], 1);
  __syncthreads();

  // ---- P4: final BN2+relu on group max/min, store [B,128,NP] (np coalesced)
  for (u32 e = (u32)cb*1024u + t; e < 16u*1024u*128u; e += (u32)NCB*1024u){
    u32 np = e & 1023u;
    u32 c  = (e >> 10) & 127u;
    u32 b  = e >> 17;
    size_t gi = ((size_t)b*1024 + np)*128 + c;
    float a = a2[c];
    float v = (a >= 0.f) ? maxb[gi] : minb[gi];
    out1[((size_t)b*128 + c)*1024 + np] = fmaxf(fmaf(a, v, d2[c]), 0.f);
  }
}

// ---------------------------------------------------------------- launch
extern "C" void kernel_launch(void* const* d_in, const int* in_sizes, int n_in,
                              void* d_out, int out_size, void* d_ws, size_t ws_size,
                              hipStream_t stream) {
  const float* xyz    = (const float*)d_in[0];
  const float* points = (const float*)d_in[1];
  const int*   finit  = (const int*)d_in[2];
  const int*   gidx   = (const int*)d_in[3];
  const float* W0  = (const float*)d_in[4];
  const float* g0v = (const float*)d_in[6];
  const float* be0 = (const float*)d_in[7];
  const float* W1  = (const float*)d_in[8];
  const float* g1v = (const float*)d_in[10];
  const float* be1 = (const float*)d_in[11];
  const float* W2  = (const float*)d_in[12];
  const float* g2v = (const float*)d_in[14];
  const float* be2 = (const float*)d_in[15];

  float* out0 = (float*)d_out;
  float* out1 = out0 + 16*3*NPOINT;   // 49152

  char* ws = (char*)d_ws;
  // layout (bytes):
  //   [0, 128M)            y1 (l1 out); XP aliases [0,48M) (dead before l1 writes)
  //   [128M, 192M)         y0 (l0 out); maxb/minb alias (y0 dead after l1)
  //   [192M, ...)          statsF, W*bf, ctrs
  u16* y1 = (u16*)ws;
  u16* XP = (u16*)ws;
  u16* y0 = (u16*)(ws + 134217728);
  float* maxb = (float*)(ws + 134217728);
  float* minb = (float*)(ws + 134217728 + 8388608);
  float* statsF = (float*)(ws + 201326592);
  u16* W0bf = (u16*)(ws + 201326592 + 49920*4);          // 201526272
  u16* W1bf = W0bf + 64*96;
  u16* W2bf = W1bf + 128*64;
  u32* ctrs = (u32*)(ws + 205782016);                    // 64 u32

  zero_kernel<<<1, 64, 0, stream>>>(ctrs);
  mega_kernel<<<256, 1024, 0, stream>>>(
      xyz, points, finit, gidx,
      W0, g0v, be0, W1, g1v, be1, W2, g2v, be2,
      out0, out1, XP, y0, y1, maxb, minb, statsF,
      W0bf, W1bf, W2bf, ctrs);
}